// Round 8
// baseline (215.982 us; speedup 1.0000x reference)
//
#include <hip/hip_runtime.h>

constexpr int NN = 100000;   // nodes
constexpr int NE = 1600000;  // edges
constexpr int F  = 64;       // F_IN == F_OUT

typedef short bf16x8 __attribute__((ext_vector_type(8)));
typedef float f32x4  __attribute__((ext_vector_type(4)));
typedef unsigned int u32x4 __attribute__((ext_vector_type(4)));
typedef int   i32x2 __attribute__((ext_vector_type(2)));

// bf16 helpers: bf16 bits<<16 == fp32 bit pattern.
__device__ __forceinline__ float bf_lo(unsigned u) { return __uint_as_float(u << 16); }
__device__ __forceinline__ float bf_hi(unsigned u) { return __uint_as_float(u & 0xFFFF0000u); }
__device__ __forceinline__ unsigned pack_bf16(float a, float b) {  // RNE
    unsigned ua = __float_as_uint(a);
    unsigned ub = __float_as_uint(b);
    ua = (ua + 0x7FFFu + ((ua >> 16) & 1u)) >> 16;
    ub = (ub + 0x7FFFu + ((ub >> 16) & 1u)) & 0xFFFF0000u;
    return ua | ub;
}

// ---------------------------------------------------------------------------
// K1 prep: ONE dispatch, partitioned by blockIdx:
//   [0,3125):      x fp32 -> bf16 (nt-load x: single use)
//   [3125,9375):   per-edge: row_ptr boundary scatter + ev[e]=(col,val)
//                  (nt-store ev: consumed much later, streamed)
//   [9375,9423):   W [192][64] fp32 -> Wt [64][192] bf16 (transposed)
// ---------------------------------------------------------------------------
constexpr int B_CVT = NN * F / 8 / 256;        // 3125
constexpr int B_RP  = NE / 256;                // 6250
constexpr int B_W   = 192 * 64 / 256;          // 48

__global__ __launch_bounds__(256)
void prep_k(const float* __restrict__ x, ushort* __restrict__ xb,
            const int* __restrict__ rows, const int* __restrict__ cols,
            const float* __restrict__ vals, int* __restrict__ row_ptr,
            int* __restrict__ ev, const float* __restrict__ w,
            ushort* __restrict__ wt) {
    const int b = blockIdx.x;
    if (b < B_CVT) {
        int tid = b * 256 + threadIdx.x;
        const f32x4* p = (const f32x4*)x + (size_t)tid * 2;
        f32x4 a = __builtin_nontemporal_load(p);
        f32x4 c = __builtin_nontemporal_load(p + 1);
        u32x4 o = { pack_bf16(a.x, a.y), pack_bf16(a.z, a.w),
                    pack_bf16(c.x, c.y), pack_bf16(c.z, c.w) };
        ((u32x4*)xb)[tid] = o;
    } else if (b < B_CVT + B_RP) {
        int e = (b - B_CVT) * 256 + threadIdx.x;
        int r1 = __builtin_nontemporal_load(rows + e);
        i32x2 m = { __builtin_nontemporal_load(cols + e),
                    (int)__float_as_int(__builtin_nontemporal_load(vals + e)) };
        __builtin_nontemporal_store(m, (i32x2*)(ev + 2 * (size_t)e));
        int r2 = (e == NE - 1) ? NN : rows[e + 1];
        for (int r = r1 + 1; r <= r2; ++r) row_ptr[r] = e + 1;
        if (e == 0)
            for (int r = 0; r <= r1; ++r) row_ptr[r] = 0;
    } else {
        int tid = (b - B_CVT - B_RP) * 256 + threadIdx.x;
        int k = tid >> 6, n = tid & 63;
        unsigned u = __float_as_uint(w[tid]);
        u = (u + 0x7FFFu + ((u >> 16) & 1u)) >> 16;
        wt[n * 192 + k] = (ushort)u;
    }
}

// ---------------------------------------------------------------------------
// K2/K3: reduction-free bf16 SpMM. 8 rows per wave: g = lane>>3 OWNS its row
// (no cross-lane reduction, no DS), fgrp = lane&7 covers 8 features via one
// 16B load. Loop to wave-max degree; inactive slots clamp to last edge
// (L1-hit re-read, vj=0). unroll 8 => 8 outstanding gathers/lane.
// Cache policy: ev is nt-loaded (single-use stream), dst is nt-stored
// (single later consumer) => L2 stays reserved for the random src gathers.
// SECOND: dst = 2*A@src - x0 (Chebyshev fused).
// ---------------------------------------------------------------------------
template<bool SECOND>
__global__ __launch_bounds__(256)
void spmm_k(const int* __restrict__ row_ptr, const int* __restrict__ ev,
            const ushort* __restrict__ src, const ushort* __restrict__ x0,
            ushort* __restrict__ dst) {
    const int lane = threadIdx.x & 63;
    const int fgrp = lane & 7;
    const int g    = lane >> 3;
    const int r    = (blockIdx.x * 4 + (threadIdx.x >> 6)) * 8 + g;  // < NN
    const int e0 = row_ptr[r];
    const int e1 = row_ptr[r + 1];
    const int deg = e1 - e0;
    int maxdeg = deg;
    maxdeg = max(maxdeg, __shfl_xor(maxdeg, 8));
    maxdeg = max(maxdeg, __shfl_xor(maxdeg, 16));
    maxdeg = max(maxdeg, __shfl_xor(maxdeg, 32));

    float acc[8] = {};
    #pragma unroll 8
    for (int s = 0; s < maxdeg; ++s) {
        const bool act = s < deg;
        int ec = act ? (e0 + s) : (e1 - 1);
        ec = ec < 0 ? 0 : ec;
        const i32x2 em = __builtin_nontemporal_load((const i32x2*)(ev + 2 * (size_t)ec));
        const float vj = act ? __int_as_float(em.y) : 0.f;
        u32x4 raw = *(const u32x4*)(src + (size_t)em.x * F + fgrp * 8);
        acc[0] += vj * bf_lo(raw.x); acc[1] += vj * bf_hi(raw.x);
        acc[2] += vj * bf_lo(raw.y); acc[3] += vj * bf_hi(raw.y);
        acc[4] += vj * bf_lo(raw.z); acc[5] += vj * bf_hi(raw.z);
        acc[6] += vj * bf_lo(raw.w); acc[7] += vj * bf_hi(raw.w);
    }

    float o[8];
    if (SECOND) {
        u32x4 xr = *(const u32x4*)(x0 + (size_t)r * F + fgrp * 8);
        o[0] = 2.f * acc[0] - bf_lo(xr.x); o[1] = 2.f * acc[1] - bf_hi(xr.x);
        o[2] = 2.f * acc[2] - bf_lo(xr.y); o[3] = 2.f * acc[3] - bf_hi(xr.y);
        o[4] = 2.f * acc[4] - bf_lo(xr.z); o[5] = 2.f * acc[5] - bf_hi(xr.z);
        o[6] = 2.f * acc[6] - bf_lo(xr.w); o[7] = 2.f * acc[7] - bf_hi(xr.w);
    } else {
        #pragma unroll
        for (int t = 0; t < 8; ++t) o[t] = acc[t];
    }
    u32x4 ov = { pack_bf16(o[0], o[1]), pack_bf16(o[2], o[3]),
                 pack_bf16(o[4], o[5]), pack_bf16(o[6], o[7]) };
    __builtin_nontemporal_store(ov, (u32x4*)(dst + (size_t)r * F + fgrp * 8));
}

// ---------------------------------------------------------------------------
// K4: dense epilogue via bf16 MFMA (round-5 proven version).
// out = [x|t1|t2](bf16, Nx192) @ Wt^T + bias, fp32 out.
// Wave wv: rows [blk*64+16wv, +16), all 64 cols. A/B frags = one 16B load
// each; A-rows nt-loaded (single use). C/D: col=lane&15, row=quad*4+reg.
// Epilogue via per-wave LDS slab (stride 68: 16B-aligned, 2-way banks free)
// -> coalesced nt float4 row stores.
// ---------------------------------------------------------------------------
__global__ __launch_bounds__(256)
void dense_k(const ushort* __restrict__ xb, const ushort* __restrict__ t1,
             const ushort* __restrict__ t2, const ushort* __restrict__ wt,
             const float* __restrict__ bias, float* __restrict__ out) {
    __shared__ float slab[4][16 * 68];
    const int tid  = threadIdx.x;
    const int lane = tid & 63;
    const int wv   = tid >> 6;
    const int row0 = blockIdx.x * 64 + wv * 16;
    const int m    = lane & 15;
    const int quad = lane >> 4;
    const int arow = min(row0 + m, NN - 1);   // clamp; stores guarded

    f32x4 acc[4] = {};
    #pragma unroll
    for (int kb = 0; kb < 6; ++kb) {
        const int kbase = kb * 32;
        const ushort* seg = (kb < 2) ? xb : (kb < 4) ? t1 : t2;
        const int off = (kbase & 63) + quad * 8;
        bf16x8 a = __builtin_nontemporal_load(
            (const bf16x8*)(seg + (size_t)arow * F + off));
        #pragma unroll
        for (int t = 0; t < 4; ++t) {
            const int n = t * 16 + m;
            bf16x8 b = *(const bf16x8*)(wt + (size_t)n * 192 + kbase + quad * 8);
            acc[t] = __builtin_amdgcn_mfma_f32_16x16x32_bf16(a, b, acc[t], 0, 0, 0);
        }
    }

    float* sl = slab[wv];
    #pragma unroll
    for (int t = 0; t < 4; ++t) {
        const float bv = bias[t * 16 + m];
        #pragma unroll
        for (int rr = 0; rr < 4; ++rr)
            sl[(quad * 4 + rr) * 68 + t * 16 + m] = acc[t][rr] + bv;
    }
    __syncthreads();
    const int m4 = (lane & 15) * 4;
    #pragma unroll
    for (int p = 0; p < 4; ++p) {
        const int rl = p * 4 + (lane >> 4);
        const int grow = row0 + rl;
        f32x4 v = *(const f32x4*)(sl + rl * 68 + m4);
        if (grow < NN)
            __builtin_nontemporal_store(v, (f32x4*)(out + (size_t)grow * F + m4));
    }
}

extern "C" void kernel_launch(void* const* d_in, const int* in_sizes, int n_in,
                              void* d_out, int out_size, void* d_ws, size_t ws_size,
                              hipStream_t stream) {
    const float* x    = (const float*)d_in[0];
    const int*   rows = (const int*)  d_in[1];
    const int*   cols = (const int*)  d_in[2];
    const float* vals = (const float*)d_in[3];
    const float* w    = (const float*)d_in[4];  // [3][64][64] == [192][64]
    const float* bias = (const float*)d_in[5];  // [64]
    float* out = (float*)d_out;

    // Workspace (fully rewritten every call; safe vs 0xAA poison):
    //   row_ptr (NN+1 int) | xb, t1b, t2b (12.8MB each) | wt (24KB) | ev (12.8MB)
    char* ws = (char*)d_ws;
    int* row_ptr = (int*)ws;
    size_t off = (((size_t)(NN + 1) * sizeof(int)) + 255) & ~(size_t)255;
    ushort* xb  = (ushort*)(ws + off);
    ushort* t1b = xb  + (size_t)NN * F;
    ushort* t2b = t1b + (size_t)NN * F;
    ushort* wt  = t2b + (size_t)NN * F;
    int*    ev  = (int*)(wt + 192 * 64);

    prep_k<<<B_CVT + B_RP + B_W, 256, 0, stream>>>(x, xb, rows, cols, vals,
                                                   row_ptr, ev, w, wt);
    spmm_k<false><<<NN / 32, 256, 0, stream>>>(row_ptr, ev, xb,  nullptr, t1b);
    spmm_k<true ><<<NN / 32, 256, 0, stream>>>(row_ptr, ev, t1b, xb,      t2b);
    dense_k<<<(NN + 63) / 64, 256, 0, stream>>>(xb, t1b, t2b, wt, bias, out);
}

// Round 9
// 196.502 us; speedup vs baseline: 1.0991x; 1.0991x over previous
//
#include <hip/hip_runtime.h>

constexpr int NN = 100000;   // nodes
constexpr int NE = 1600000;  // edges
constexpr int F  = 64;       // F_IN == F_OUT

typedef short bf16x8 __attribute__((ext_vector_type(8)));
typedef float f32x4  __attribute__((ext_vector_type(4)));

// bf16 helpers: bf16 bits<<16 == fp32 bit pattern.
__device__ __forceinline__ float bf_lo(unsigned u) { return __uint_as_float(u << 16); }
__device__ __forceinline__ float bf_hi(unsigned u) { return __uint_as_float(u & 0xFFFF0000u); }
__device__ __forceinline__ unsigned pack_bf16(float a, float b) {  // RNE
    unsigned ua = __float_as_uint(a);
    unsigned ub = __float_as_uint(b);
    ua = (ua + 0x7FFFu + ((ua >> 16) & 1u)) >> 16;
    ub = (ub + 0x7FFFu + ((ub >> 16) & 1u)) & 0xFFFF0000u;
    return ua | ub;
}

// ---------------------------------------------------------------------------
// K1 prep: ONE dispatch, partitioned by blockIdx (round-5 proven version,
// all nt hints removed — they raised FETCH 93->123MB in round 8):
//   [0,3125):      x fp32 -> bf16
//   [3125,9375):   per-edge: row_ptr boundary scatter + ev[e]=(col,val)
//   [9375,9423):   W [192][64] fp32 -> Wt [64][192] bf16 (transposed)
// ---------------------------------------------------------------------------
constexpr int B_CVT = NN * F / 8 / 256;        // 3125
constexpr int B_RP  = NE / 256;                // 6250
constexpr int B_W   = 192 * 64 / 256;          // 48

__global__ __launch_bounds__(256)
void prep_k(const float* __restrict__ x, ushort* __restrict__ xb,
            const int* __restrict__ rows, const int* __restrict__ cols,
            const float* __restrict__ vals, int* __restrict__ row_ptr,
            int2* __restrict__ ev, const float* __restrict__ w,
            ushort* __restrict__ wt) {
    const int b = blockIdx.x;
    if (b < B_CVT) {
        int tid = b * 256 + threadIdx.x;
        const float4* p = (const float4*)x + (size_t)tid * 2;
        float4 a = p[0], c = p[1];
        uint4 o = make_uint4(pack_bf16(a.x, a.y), pack_bf16(a.z, a.w),
                             pack_bf16(c.x, c.y), pack_bf16(c.z, c.w));
        ((uint4*)xb)[tid] = o;
    } else if (b < B_CVT + B_RP) {
        int e = (b - B_CVT) * 256 + threadIdx.x;
        int r1 = rows[e];
        ev[e] = make_int2(cols[e], __float_as_int(vals[e]));
        int r2 = (e == NE - 1) ? NN : rows[e + 1];
        for (int r = r1 + 1; r <= r2; ++r) row_ptr[r] = e + 1;
        if (e == 0)
            for (int r = 0; r <= r1; ++r) row_ptr[r] = 0;
    } else {
        int tid = (b - B_CVT - B_RP) * 256 + threadIdx.x;
        int k = tid >> 6, n = tid & 63;
        unsigned u = __float_as_uint(w[tid]);
        u = (u + 0x7FFFu + ((u >> 16) & 1u)) >> 16;
        wt[n * 192 + k] = (ushort)u;
    }
}

// ---------------------------------------------------------------------------
// K2/K3: reduction-free bf16 SpMM. 8 rows per wave: g = lane>>3 OWNS its row
// (no cross-lane reduction, no DS pipe use), fgrp = lane&7 covers 8 features
// via one 16B load. Loop to wave-max degree; inactive slots clamp to last
// edge (L1-hot re-read, vj=0).
// ROUND-9 EXPERIMENT: unroll 8 (was 2). Theory: 386 cyc/step >> issue cost;
// gather is outstanding-miss limited (~45% HBM-miss at ~570cyc avg needs ~47
// in-flight lines/CU). 8 address-independent gathers per wave in flight
// should push toward the MSHR/bandwidth wall. No nt hints (falsified r8).
// SECOND: dst = 2*A@src - x0 (Chebyshev fused).
// ---------------------------------------------------------------------------
template<bool SECOND>
__global__ __launch_bounds__(256)
void spmm_k(const int* __restrict__ row_ptr, const int2* __restrict__ ev,
            const ushort* __restrict__ src, const ushort* __restrict__ x0,
            ushort* __restrict__ dst) {
    const int lane = threadIdx.x & 63;
    const int fgrp = lane & 7;
    const int g    = lane >> 3;
    const int r    = (blockIdx.x * 4 + (threadIdx.x >> 6)) * 8 + g;  // < NN
    const int e0 = row_ptr[r];
    const int e1 = row_ptr[r + 1];
    const int deg = e1 - e0;
    int maxdeg = deg;
    maxdeg = max(maxdeg, __shfl_xor(maxdeg, 8));
    maxdeg = max(maxdeg, __shfl_xor(maxdeg, 16));
    maxdeg = max(maxdeg, __shfl_xor(maxdeg, 32));

    float acc[8] = {};
    #pragma unroll 8
    for (int s = 0; s < maxdeg; ++s) {
        const bool act = s < deg;
        int ec = act ? (e0 + s) : (e1 - 1);
        ec = ec < 0 ? 0 : ec;
        const int2 em = ev[ec];
        const float vj = act ? __int_as_float(em.y) : 0.f;
        uint4 raw = *(const uint4*)(src + (size_t)em.x * F + fgrp * 8);
        acc[0] += vj * bf_lo(raw.x); acc[1] += vj * bf_hi(raw.x);
        acc[2] += vj * bf_lo(raw.y); acc[3] += vj * bf_hi(raw.y);
        acc[4] += vj * bf_lo(raw.z); acc[5] += vj * bf_hi(raw.z);
        acc[6] += vj * bf_lo(raw.w); acc[7] += vj * bf_hi(raw.w);
    }

    float o[8];
    if (SECOND) {
        uint4 xr = *(const uint4*)(x0 + (size_t)r * F + fgrp * 8);
        o[0] = 2.f * acc[0] - bf_lo(xr.x); o[1] = 2.f * acc[1] - bf_hi(xr.x);
        o[2] = 2.f * acc[2] - bf_lo(xr.y); o[3] = 2.f * acc[3] - bf_hi(xr.y);
        o[4] = 2.f * acc[4] - bf_lo(xr.z); o[5] = 2.f * acc[5] - bf_hi(xr.z);
        o[6] = 2.f * acc[6] - bf_lo(xr.w); o[7] = 2.f * acc[7] - bf_hi(xr.w);
    } else {
        #pragma unroll
        for (int t = 0; t < 8; ++t) o[t] = acc[t];
    }
    uint4 ov = make_uint4(pack_bf16(o[0], o[1]), pack_bf16(o[2], o[3]),
                          pack_bf16(o[4], o[5]), pack_bf16(o[6], o[7]));
    *(uint4*)(dst + (size_t)r * F + fgrp * 8) = ov;
}

// ---------------------------------------------------------------------------
// K4: dense epilogue via bf16 MFMA (round-5 proven version, no nt).
// out = [x|t1|t2](bf16, Nx192) @ Wt^T + bias, fp32 out.
// Wave wv: rows [blk*64+16wv, +16), all 64 cols. A/B frags = one 16B load
// each. C/D: col=lane&15, row=quad*4+reg. Epilogue via per-wave LDS slab
// (stride 68: 16B-aligned, 2-way banks free) -> coalesced float4 row stores.
// ---------------------------------------------------------------------------
__global__ __launch_bounds__(256)
void dense_k(const ushort* __restrict__ xb, const ushort* __restrict__ t1,
             const ushort* __restrict__ t2, const ushort* __restrict__ wt,
             const float* __restrict__ bias, float* __restrict__ out) {
    __shared__ float slab[4][16 * 68];
    const int tid  = threadIdx.x;
    const int lane = tid & 63;
    const int wv   = tid >> 6;
    const int row0 = blockIdx.x * 64 + wv * 16;
    const int m    = lane & 15;
    const int quad = lane >> 4;
    const int arow = min(row0 + m, NN - 1);   // clamp; stores guarded

    f32x4 acc[4] = {};
    #pragma unroll
    for (int kb = 0; kb < 6; ++kb) {
        const int kbase = kb * 32;
        const ushort* seg = (kb < 2) ? xb : (kb < 4) ? t1 : t2;
        const int off = (kbase & 63) + quad * 8;
        bf16x8 a = *(const bf16x8*)(seg + (size_t)arow * F + off);
        #pragma unroll
        for (int t = 0; t < 4; ++t) {
            const int n = t * 16 + m;
            bf16x8 b = *(const bf16x8*)(wt + (size_t)n * 192 + kbase + quad * 8);
            acc[t] = __builtin_amdgcn_mfma_f32_16x16x32_bf16(a, b, acc[t], 0, 0, 0);
        }
    }

    float* sl = slab[wv];
    #pragma unroll
    for (int t = 0; t < 4; ++t) {
        const float bv = bias[t * 16 + m];
        #pragma unroll
        for (int rr = 0; rr < 4; ++rr)
            sl[(quad * 4 + rr) * 68 + t * 16 + m] = acc[t][rr] + bv;
    }
    __syncthreads();
    const int m4 = (lane & 15) * 4;
    #pragma unroll
    for (int p = 0; p < 4; ++p) {
        const int rl = p * 4 + (lane >> 4);
        const int grow = row0 + rl;
        f32x4 v = *(const f32x4*)(sl + rl * 68 + m4);
        if (grow < NN)
            *(f32x4*)(out + (size_t)grow * F + m4) = v;
    }
}

extern "C" void kernel_launch(void* const* d_in, const int* in_sizes, int n_in,
                              void* d_out, int out_size, void* d_ws, size_t ws_size,
                              hipStream_t stream) {
    const float* x    = (const float*)d_in[0];
    const int*   rows = (const int*)  d_in[1];
    const int*   cols = (const int*)  d_in[2];
    const float* vals = (const float*)d_in[3];
    const float* w    = (const float*)d_in[4];  // [3][64][64] == [192][64]
    const float* bias = (const float*)d_in[5];  // [64]
    float* out = (float*)d_out;

    // Workspace (fully rewritten every call; safe vs 0xAA poison):
    //   row_ptr (NN+1 int) | xb, t1b, t2b (12.8MB each) | wt (24KB) | ev (12.8MB)
    char* ws = (char*)d_ws;
    int* row_ptr = (int*)ws;
    size_t off = (((size_t)(NN + 1) * sizeof(int)) + 255) & ~(size_t)255;
    ushort* xb  = (ushort*)(ws + off);
    ushort* t1b = xb  + (size_t)NN * F;
    ushort* t2b = t1b + (size_t)NN * F;
    ushort* wt  = t2b + (size_t)NN * F;
    int2*   ev  = (int2*)(wt + 192 * 64);

    prep_k<<<B_CVT + B_RP + B_W, 256, 0, stream>>>(x, xb, rows, cols, vals,
                                                   row_ptr, ev, w, wt);
    spmm_k<false><<<NN / 32, 256, 0, stream>>>(row_ptr, ev, xb,  nullptr, t1b);
    spmm_k<true ><<<NN / 32, 256, 0, stream>>>(row_ptr, ev, t1b, xb,      t2b);
    dense_k<<<(NN + 63) / 64, 256, 0, stream>>>(xb, t1b, t2b, wt, bias, out);
}